// Round 9
// baseline (134.099 us; speedup 1.0000x reference)
//
#include <hip/hip_runtime.h>
#include <math.h>

#define SEQ   100
#define BATCH 256
#define NREP  8
#define FFD   2048
#define RSQRT2 0.70710678118654752440f

__device__ __forceinline__ float wsum(float v) {
#pragma unroll
  for (int o = 32; o > 0; o >>= 1) v += __shfl_xor(v, o, 64);
  return v;
}

// ---------------------------------------------------------------- prep
// W2T[l][f][d] = W2[l][d][f]  (one-time transpose so FFN reads are float4)
__global__ __launch_bounds__(256) void k_prep(
    const float* __restrict__ W2, float* __restrict__ W2T)
{
  const int id = blockIdx.x * 256 + threadIdx.x;   // l*2048+f, 8192 total
  const float* src = W2 + (id >> 11) * 4 * FFD + (id & 2047);
  *(float4*)(W2T + id * 4) =
      make_float4(src[0], src[FFD], src[2 * FFD], src[3 * FFD]);
}

// ---------------------------------------------------------------- stage A
__global__ __launch_bounds__(64) void k_stageA(
    const float* __restrict__ x, const float* __restrict__ convw,
    const float* __restrict__ convb, const float* __restrict__ Wl,
    const float* __restrict__ bl, const float* __restrict__ lng,
    const float* __restrict__ lnb, float* __restrict__ XT)
{
  const int b = blockIdx.x;
  const int lane = threadIdx.x;
  const bool act = lane < 50;

  const float cw = convw[0], cb = convb[0];
  float W[4][4], B[4];
#pragma unroll
  for (int j = 0; j < 4; ++j) {
    B[j] = bl[j];
#pragma unroll
    for (int d = 0; d < 4; ++d) W[j][d] = Wl[j * 4 + d];
  }
  float h[2][4] = {{0.f,0.f,0.f,0.f},{0.f,0.f,0.f,0.f}};
  float gg[2][4] = {{0.f}}, eb[2][4] = {{0.f}};
  if (act) {
#pragma unroll
    for (int p = 0; p < 2; ++p) {
      const int r = lane * 2 + p;
      float4 xr = *(const float4*)(x + (b * SEQ + r) * 4);
      h[p][0] = fmaf(xr.x, cw, cb); h[p][1] = fmaf(xr.y, cw, cb);
      h[p][2] = fmaf(xr.z, cw, cb); h[p][3] = fmaf(xr.w, cw, cb);
      float4 gv = *(const float4*)(lng + r * 4);
      float4 bv = *(const float4*)(lnb + r * 4);
      gg[p][0] = gv.x; gg[p][1] = gv.y; gg[p][2] = gv.z; gg[p][3] = gv.w;
      eb[p][0] = bv.x; eb[p][1] = bv.y; eb[p][2] = bv.z; eb[p][3] = bv.w;
    }
  }
  for (int it = 0; it < NREP; ++it) {
    float y[2][4] = {{0.f,0.f,0.f,0.f},{0.f,0.f,0.f,0.f}};
    float s1 = 0.f, s2 = 0.f;
    if (act) {
#pragma unroll
      for (int p = 0; p < 2; ++p)
#pragma unroll
        for (int j = 0; j < 4; ++j) {
          float yy = B[j];
#pragma unroll
          for (int d = 0; d < 4; ++d) yy = fmaf(h[p][d], W[j][d], yy);
          y[p][j] = yy; s1 += yy; s2 = fmaf(yy, yy, s2);
        }
    }
    s1 = wsum(s1); s2 = wsum(s2);
    const float mean = s1 * (1.0f / 400.0f);
    const float var  = s2 * (1.0f / 400.0f) - mean * mean;
    const float rstd = rsqrtf(var + 1e-5f);
    if (act) {
#pragma unroll
      for (int p = 0; p < 2; ++p)
#pragma unroll
        for (int j = 0; j < 4; ++j) {
          float vv = fmaf((y[p][j] - mean) * rstd, gg[p][j], eb[p][j]);
          h[p][j] = 0.5f * vv * (1.0f + erff(vv * RSQRT2));
        }
    }
  }
  if (act) {
#pragma unroll
    for (int p = 0; p < 2; ++p) {
      const int r = lane * 2 + p;
      float yy[4];
#pragma unroll
      for (int j = 0; j < 4; ++j) {
        float a = B[j];
#pragma unroll
        for (int d = 0; d < 4; ++d) a = fmaf(h[p][d], W[j][d], a);
        yy[j] = a;
      }
      *(float4*)(XT + (r * BATCH + b) * 4) =
          make_float4(yy[0], yy[1], yy[2], yy[3]);
    }
  }
}

// ---------------------------------------------------------------- layer
// block = (column n, batch-half); 200 blocks x 1024 threads (16 waves).
// attn: wave = (head, key-quarter), lane-rotated distinct kv reads.
// FFN:  wave owns 8 rows, lane owns 32 f; weights coalesced from global
//       (W1 [f][4], W2T [f][4], b1); butterfly reduce over lanes.
__global__ __launch_bounds__(1024, 4) void k_layer(
    const float* __restrict__ XTin, float* __restrict__ XTout,
    const float* __restrict__ Wa,  const float* __restrict__ ba,
    const float* __restrict__ Wo,  const float* __restrict__ bo,
    const float* __restrict__ W1l, const float* __restrict__ b1l,
    const float* __restrict__ W2Tl,const float* __restrict__ b2l,
    const float* __restrict__ g1l, const float* __restrict__ e1l,
    const float* __restrict__ g2l, const float* __restrict__ e2l,
    const float* __restrict__ Wl,  const float* __restrict__ bl,
    float* __restrict__ out, const int last)
{
  const int n      = blockIdx.x;        // column 0..99
  const int base_s = blockIdx.y * 128;  // batch half
  const int t      = threadIdx.x;       // 0..1023
  const int lane   = t & 63;
  const int wv     = t >> 6;            // 0..15
  const int ah     = wv & 3;            // attn head (wave-uniform)
  const int kq     = wv >> 2;           // key quarter 0..3 (wave-uniform)

  __shared__ __align__(16) float2 kv[4][256];      // 8 KB
  __shared__ float2 part[4][128][5];               // 20 KB (pad 4->5)
  __shared__ float  osm[4][128];                   // 2 KB
  __shared__ float  x1s[128][4];                   // 2 KB
  __shared__ float  fout[128][4];                  // 2 KB
  __shared__ float2 kred[4][4];

  // ---- K,V for the whole column: thread = (head = t>>8, s = t&255)
  {
    const int s = t & 255, hh = t >> 8;
    float4 xr = *(const float4*)(XTin + (n * BATCH + s) * 4);
    const float* wk = Wa + (4 + hh) * 4;
    const float* wp = Wa + (8 + hh) * 4;
    float k = ba[4+hh] + xr.x*wk[0] + xr.y*wk[1] + xr.z*wk[2] + xr.w*wk[3];
    float v = ba[8+hh] + xr.x*wp[0] + xr.y*wp[1] + xr.z*wp[2] + xr.w*wp[3];
    kv[hh][s] = make_float2(k, v);
  }
  // ---- q for own rows qr0 = 2*lane, qr1 = 2*lane+1 (head ah)
  float q0, q1;
  {
    const float* wq = Wa + ah * 4;
    float4 xa = *(const float4*)(XTin + (n * BATCH + base_s + 2 * lane) * 4);
    float4 xb = *(const float4*)(XTin + (n * BATCH + base_s + 2 * lane + 1) * 4);
    q0 = ba[ah] + xa.x*wq[0] + xa.y*wq[1] + xa.z*wq[2] + xa.w*wq[3];
    q1 = ba[ah] + xb.x*wq[0] + xb.y*wq[1] + xb.z*wq[2] + xb.w*wq[3];
  }
  __syncthreads();

  // ---- per-(head,quarter) k max/min
  {
    float k = kv[ah][kq * 64 + lane].x;
    float mx = k, mn = k;
#pragma unroll
    for (int o = 32; o > 0; o >>= 1) {
      mx = fmaxf(mx, __shfl_xor(mx, o, 64));
      mn = fminf(mn, __shfl_xor(mn, o, 64));
    }
    if (lane == 0) kred[ah][kq] = make_float2(mx, mn);
  }
  __syncthreads();

  // ---- attention: thread covers 64 keys [kq*64, kq*64+64) for 2 rows;
  //      lane-rotated float4 reads (2 keys each), conflict-free.
  {
    const float kmx = fmaxf(fmaxf(kred[ah][0].x, kred[ah][1].x),
                            fmaxf(kred[ah][2].x, kred[ah][3].x));
    const float kmn = fminf(fminf(kred[ah][0].y, kred[ah][1].y),
                            fminf(kred[ah][2].y, kred[ah][3].y));
    const float m0 = (q0 >= 0.f) ? q0 * kmx : q0 * kmn;
    const float m1 = (q1 >= 0.f) ? q1 * kmx : q1 * kmn;
    const int kb = kq * 64;
    float dA = 0.f, nA = 0.f, dB = 0.f, nB = 0.f;
#pragma unroll 4
    for (int i = 0; i < 32; ++i) {
      const int p = ((lane + i) & 31) * 2;
      float4 kk = *(const float4*)&kv[ah][kb + p];   // k0 v0 k1 v1
      float pA0 = __expf(fmaf(q0, kk.x, -m0));
      float pA1 = __expf(fmaf(q0, kk.z, -m0));
      float pB0 = __expf(fmaf(q1, kk.x, -m1));
      float pB1 = __expf(fmaf(q1, kk.z, -m1));
      dA += pA0 + pA1; nA = fmaf(pA1, kk.w, fmaf(pA0, kk.y, nA));
      dB += pB0 + pB1; nB = fmaf(pB1, kk.w, fmaf(pB0, kk.y, nB));
    }
    part[ah][2 * lane][kq]     = make_float2(dA, nA);
    part[ah][2 * lane + 1][kq] = make_float2(dB, nB);
  }
  __syncthreads();

  // ---- combine quarters (threads 0..511): h = t>>7, qr = t&127
  if (t < 512) {
    const int h = t >> 7, qr = t & 127;
    float2 a = part[h][qr][0], b = part[h][qr][1];
    float2 c = part[h][qr][2], d = part[h][qr][3];
    osm[h][qr] = (a.y + b.y + c.y + d.y) / (a.x + b.x + c.x + d.x);
  }
  __syncthreads();

  // ---- Wout proj + residual + LN1 : threads 0..511 -> (r = t>>2, d = t&3)
  if (t < 512) {
    const int r = t >> 2, d = t & 3;
    const float o0 = osm[0][r], o1 = osm[1][r], o2 = osm[2][r], o3 = osm[3][r];
    float rr = XTin[(n * BATCH + base_s + r) * 4 + d] + bo[d]
             + o0*Wo[d*4+0] + o1*Wo[d*4+1] + o2*Wo[d*4+2] + o3*Wo[d*4+3];
    float sum = rr + __shfl_xor(rr, 1, 64); sum += __shfl_xor(sum, 2, 64);
    const float mean = 0.25f * sum;
    const float dv = rr - mean;
    float qq = dv * dv;
    float qs = qq + __shfl_xor(qq, 1, 64); qs += __shfl_xor(qs, 2, 64);
    const float rstd = rsqrtf(0.25f * qs + 1e-5f);
    x1s[r][d] = fmaf(dv * rstd, g1l[d], e1l[d]);
  }
  __syncthreads();

  // ---- FFN: wave wv owns rows [wv*8, wv*8+8); lane owns f = 64j + lane
  {
    const int r0 = wv * 8;
    float xr[8][4];
#pragma unroll
    for (int rr = 0; rr < 8; ++rr) {
      float4 v = *(const float4*)&x1s[r0 + rr][0];
      xr[rr][0] = v.x; xr[rr][1] = v.y; xr[rr][2] = v.z; xr[rr][3] = v.w;
    }
    float acc[8][4] = {{0.f,0.f,0.f,0.f},{0.f,0.f,0.f,0.f},
                       {0.f,0.f,0.f,0.f},{0.f,0.f,0.f,0.f},
                       {0.f,0.f,0.f,0.f},{0.f,0.f,0.f,0.f},
                       {0.f,0.f,0.f,0.f},{0.f,0.f,0.f,0.f}};
    const float* w1p = W1l + lane * 4;
    const float* w2p = W2Tl + lane * 4;
    const float* b1p = b1l + lane;
#pragma unroll 4
    for (int j = 0; j < 32; ++j) {
      const float4 w1 = *(const float4*)(w1p + j * 256);
      const float4 w2 = *(const float4*)(w2p + j * 256);
      const float  bb = b1p[j * 64];
#pragma unroll
      for (int rr = 0; rr < 8; ++rr) {
        float hh = fmaf(xr[rr][3], w1.w, fmaf(xr[rr][2], w1.z,
                   fmaf(xr[rr][1], w1.y, fmaf(xr[rr][0], w1.x, bb))));
        hh = fmaxf(hh, 0.f);
        acc[rr][0] = fmaf(hh, w2.x, acc[rr][0]);
        acc[rr][1] = fmaf(hh, w2.y, acc[rr][1]);
        acc[rr][2] = fmaf(hh, w2.z, acc[rr][2]);
        acc[rr][3] = fmaf(hh, w2.w, acc[rr][3]);
      }
    }
    // butterfly-sum each of the 32 accumulators over all 64 lanes
#pragma unroll
    for (int rr = 0; rr < 8; ++rr)
#pragma unroll
      for (int d = 0; d < 4; ++d) {
        float v = acc[rr][d];
#pragma unroll
        for (int o = 32; o > 0; o >>= 1) v += __shfl_xor(v, o, 64);
        acc[rr][d] = v;
      }
    if (lane == 0) {
#pragma unroll
      for (int rr = 0; rr < 8; ++rr)
        *(float4*)&fout[r0 + rr][0] =
            make_float4(acc[rr][0], acc[rr][1], acc[rr][2], acc[rr][3]);
    }
  }
  __syncthreads();

  // ---- residual + LN2 : threads 0..511 -> (r, d)
  if (t < 512) {
    const int r = t >> 2, d = t & 3;
    float val = x1s[r][d] + fout[r][d] + b2l[d];
    float sum = val + __shfl_xor(val, 1, 64); sum += __shfl_xor(sum, 2, 64);
    const float mean = 0.25f * sum;
    const float dv = val - mean;
    float qq = dv * dv;
    float qs = qq + __shfl_xor(qq, 1, 64); qs += __shfl_xor(qs, 2, 64);
    const float rstd = rsqrtf(0.25f * qs + 1e-5f);
    const float res = fmaf(dv * rstd, g2l[d], e2l[d]);
    if (!last) XTout[(n * BATCH + base_s + r) * 4 + d] = res;
    else       x1s[r][d] = res;   // own element: no race
  }

  // ---- layer 3 only: final linear + softmax over d
  if (last) {
    __syncthreads();
    if (t < 512) {
      const int r = t >> 2, j = t & 3;
      const float y = fmaf(x1s[r][3], Wl[j*4+3], fmaf(x1s[r][2], Wl[j*4+2],
                      fmaf(x1s[r][1], Wl[j*4+1], fmaf(x1s[r][0], Wl[j*4+0], bl[j]))));
      float mx = fmaxf(y, __shfl_xor(y, 1, 64)); mx = fmaxf(mx, __shfl_xor(mx, 2, 64));
      const float e = __expf(y - mx);
      float se = e + __shfl_xor(e, 1, 64); se += __shfl_xor(se, 2, 64);
      out[((base_s + r) * SEQ + n) * 4 + j] = e / se;
    }
  }
}

// ---------------------------------------------------------------- launch
extern "C" void kernel_launch(void* const* d_in, const int* in_sizes, int n_in,
                              void* d_out, int out_size, void* d_ws, size_t ws_size,
                              hipStream_t stream)
{
  const float* x     = (const float*)d_in[0];
  const float* convw = (const float*)d_in[1];
  const float* convb = (const float*)d_in[2];
  const float* Wl    = (const float*)d_in[3];
  const float* bl    = (const float*)d_in[4];
  const float* lng   = (const float*)d_in[5];
  const float* lnb   = (const float*)d_in[6];
  const float* Win   = (const float*)d_in[7];
  const float* bi    = (const float*)d_in[8];
  const float* Wout  = (const float*)d_in[9];
  const float* bout  = (const float*)d_in[10];
  const float* W1    = (const float*)d_in[11];
  const float* b1    = (const float*)d_in[12];
  const float* W2    = (const float*)d_in[13];
  const float* b2    = (const float*)d_in[14];
  const float* g1    = (const float*)d_in[15];
  const float* be1   = (const float*)d_in[16];
  const float* g2    = (const float*)d_in[17];
  const float* be2   = (const float*)d_in[18];

  float* XT0 = (float*)d_ws;                 // [100][256][4]
  float* XT1 = XT0 + SEQ * BATCH * 4;
  float* W2T = XT1 + SEQ * BATCH * 4;        // [4][2048][4]

  k_prep<<<32, 256, 0, stream>>>(W2, W2T);
  k_stageA<<<BATCH, 64, 0, stream>>>(x, convw, convb, Wl, bl, lng, lnb, XT0);
  for (int l = 0; l < 4; ++l) {
    const float* in  = (l & 1) ? XT1 : XT0;
    float*       outb= (l & 1) ? XT0 : XT1;
    k_layer<<<dim3(SEQ, 2), 1024, 0, stream>>>(
        in, outb,
        Win + l * 48, bi + l * 12, Wout + l * 16, bout + l * 4,
        W1 + l * FFD * 4, b1 + l * FFD, W2T + l * FFD * 4, b2 + l * 4,
        g1 + l * 4, be1 + l * 4, g2 + l * 4, be2 + l * 4,
        Wl, bl, (float*)d_out, (l == 3) ? 1 : 0);
  }
}

// Round 10
// 123.177 us; speedup vs baseline: 1.0887x; 1.0887x over previous
//
#include <hip/hip_runtime.h>
#include <math.h>

#define SEQ   100
#define BATCH 256
#define NREP  8
#define FFD   2048
#define RSQRT2 0.70710678118654752440f

__device__ __forceinline__ float wsum(float v) {
#pragma unroll
  for (int o = 32; o > 0; o >>= 1) v += __shfl_xor(v, o, 64);
  return v;
}

// ---------------------------------------------------------------- prep
// W2T[l][f][d] = W2[l][d][f]  (one-time transpose: scalar-load friendly)
__global__ __launch_bounds__(256) void k_prep(
    const float* __restrict__ W2, float* __restrict__ W2T)
{
  const int id = blockIdx.x * 256 + threadIdx.x;   // l*2048+f, 8192 total
  const float* src = W2 + (id >> 11) * 4 * FFD + (id & 2047);
  *(float4*)(W2T + id * 4) =
      make_float4(src[0], src[FFD], src[2 * FFD], src[3 * FFD]);
}

// ---------------------------------------------------------------- stage A
__global__ __launch_bounds__(64) void k_stageA(
    const float* __restrict__ x, const float* __restrict__ convw,
    const float* __restrict__ convb, const float* __restrict__ Wl,
    const float* __restrict__ bl, const float* __restrict__ lng,
    const float* __restrict__ lnb, float* __restrict__ XT)
{
  const int b = blockIdx.x;
  const int lane = threadIdx.x;
  const bool act = lane < 50;

  const float cw = convw[0], cb = convb[0];
  float W[4][4], B[4];
#pragma unroll
  for (int j = 0; j < 4; ++j) {
    B[j] = bl[j];
#pragma unroll
    for (int d = 0; d < 4; ++d) W[j][d] = Wl[j * 4 + d];
  }
  float h[2][4] = {{0.f,0.f,0.f,0.f},{0.f,0.f,0.f,0.f}};
  float gg[2][4] = {{0.f}}, eb[2][4] = {{0.f}};
  if (act) {
#pragma unroll
    for (int p = 0; p < 2; ++p) {
      const int r = lane * 2 + p;
      float4 xr = *(const float4*)(x + (b * SEQ + r) * 4);
      h[p][0] = fmaf(xr.x, cw, cb); h[p][1] = fmaf(xr.y, cw, cb);
      h[p][2] = fmaf(xr.z, cw, cb); h[p][3] = fmaf(xr.w, cw, cb);
      float4 gv = *(const float4*)(lng + r * 4);
      float4 bv = *(const float4*)(lnb + r * 4);
      gg[p][0] = gv.x; gg[p][1] = gv.y; gg[p][2] = gv.z; gg[p][3] = gv.w;
      eb[p][0] = bv.x; eb[p][1] = bv.y; eb[p][2] = bv.z; eb[p][3] = bv.w;
    }
  }
  for (int it = 0; it < NREP; ++it) {
    float y[2][4] = {{0.f,0.f,0.f,0.f},{0.f,0.f,0.f,0.f}};
    float s1 = 0.f, s2 = 0.f;
    if (act) {
#pragma unroll
      for (int p = 0; p < 2; ++p)
#pragma unroll
        for (int j = 0; j < 4; ++j) {
          float yy = B[j];
#pragma unroll
          for (int d = 0; d < 4; ++d) yy = fmaf(h[p][d], W[j][d], yy);
          y[p][j] = yy; s1 += yy; s2 = fmaf(yy, yy, s2);
        }
    }
    s1 = wsum(s1); s2 = wsum(s2);
    const float mean = s1 * (1.0f / 400.0f);
    const float var  = s2 * (1.0f / 400.0f) - mean * mean;
    const float rstd = rsqrtf(var + 1e-5f);
    if (act) {
#pragma unroll
      for (int p = 0; p < 2; ++p)
#pragma unroll
        for (int j = 0; j < 4; ++j) {
          float vv = fmaf((y[p][j] - mean) * rstd, gg[p][j], eb[p][j]);
          h[p][j] = 0.5f * vv * (1.0f + erff(vv * RSQRT2));
        }
    }
  }
  if (act) {
#pragma unroll
    for (int p = 0; p < 2; ++p) {
      const int r = lane * 2 + p;
      float yy[4];
#pragma unroll
      for (int j = 0; j < 4; ++j) {
        float a = B[j];
#pragma unroll
        for (int d = 0; d < 4; ++d) a = fmaf(h[p][d], W[j][d], a);
        yy[j] = a;
      }
      *(float4*)(XT + (r * BATCH + b) * 4) =
          make_float4(yy[0], yy[1], yy[2], yy[3]);
    }
  }
}

// ---------------------------------------------------------------- layer
// block = (column n, batch-half); 200 blocks x 1024 threads (16 waves).
// attn: wave = (head, key-quarter), lane-rotated distinct kv reads.
// FFN:  wave owns a 128-f slice; lane owns rows {lane, 64+lane}; weights
//       stream through SCALAR loads (wave-uniform addr -> s_load, K$/L2),
//       latency hidden by 4 waves/SIMD; partials reduced via LDS pacc.
__global__ __launch_bounds__(1024, 4) void k_layer(
    const float* __restrict__ XTin, float* __restrict__ XTout,
    const float* __restrict__ Wa,  const float* __restrict__ ba,
    const float* __restrict__ Wo,  const float* __restrict__ bo,
    const float* __restrict__ W1l, const float* __restrict__ b1l,
    const float* __restrict__ W2Tl,const float* __restrict__ b2l,
    const float* __restrict__ g1l, const float* __restrict__ e1l,
    const float* __restrict__ g2l, const float* __restrict__ e2l,
    const float* __restrict__ Wl,  const float* __restrict__ bl,
    float* __restrict__ out, const int last)
{
  const int n      = blockIdx.x;        // column 0..99
  const int base_s = blockIdx.y * 128;  // batch half
  const int t      = threadIdx.x;       // 0..1023
  const int lane   = t & 63;
  const int wv     = t >> 6;            // 0..15
  const int ah     = wv & 3;            // attn head (wave-uniform)
  const int kq     = wv >> 2;           // key quarter 0..3 (wave-uniform)

  __shared__ __align__(16) float2 kv[4][256];      // 8 KB
  __shared__ float2 part[4][128][5];               // 20 KB (pad 4->5)
  __shared__ float  osm[4][128];                   // 2 KB
  __shared__ float  x1s[128][4];                   // 2 KB
  __shared__ float  pacc[16][128][4];              // 32 KB
  __shared__ float2 kred[4][4];

  // ---- K,V for the whole column: thread = (head = t>>8, s = t&255)
  {
    const int s = t & 255, hh = t >> 8;
    float4 xr = *(const float4*)(XTin + (n * BATCH + s) * 4);
    const float* wk = Wa + (4 + hh) * 4;
    const float* wp = Wa + (8 + hh) * 4;
    float k = ba[4+hh] + xr.x*wk[0] + xr.y*wk[1] + xr.z*wk[2] + xr.w*wk[3];
    float v = ba[8+hh] + xr.x*wp[0] + xr.y*wp[1] + xr.z*wp[2] + xr.w*wp[3];
    kv[hh][s] = make_float2(k, v);
  }
  // ---- q for own rows qr0 = 2*lane, qr1 = 2*lane+1 (head ah)
  float q0, q1;
  {
    const float* wq = Wa + ah * 4;
    float4 xa = *(const float4*)(XTin + (n * BATCH + base_s + 2 * lane) * 4);
    float4 xb = *(const float4*)(XTin + (n * BATCH + base_s + 2 * lane + 1) * 4);
    q0 = ba[ah] + xa.x*wq[0] + xa.y*wq[1] + xa.z*wq[2] + xa.w*wq[3];
    q1 = ba[ah] + xb.x*wq[0] + xb.y*wq[1] + xb.z*wq[2] + xb.w*wq[3];
  }
  __syncthreads();

  // ---- per-(head,quarter) k max/min
  {
    float k = kv[ah][kq * 64 + lane].x;
    float mx = k, mn = k;
#pragma unroll
    for (int o = 32; o > 0; o >>= 1) {
      mx = fmaxf(mx, __shfl_xor(mx, o, 64));
      mn = fminf(mn, __shfl_xor(mn, o, 64));
    }
    if (lane == 0) kred[ah][kq] = make_float2(mx, mn);
  }
  __syncthreads();

  // ---- attention: thread covers 64 keys [kq*64, +64) for rows 2lane,2lane+1
  {
    const float kmx = fmaxf(fmaxf(kred[ah][0].x, kred[ah][1].x),
                            fmaxf(kred[ah][2].x, kred[ah][3].x));
    const float kmn = fminf(fminf(kred[ah][0].y, kred[ah][1].y),
                            fminf(kred[ah][2].y, kred[ah][3].y));
    const float m0 = (q0 >= 0.f) ? q0 * kmx : q0 * kmn;
    const float m1 = (q1 >= 0.f) ? q1 * kmx : q1 * kmn;
    const int kb = kq * 64;
    float dA = 0.f, nA = 0.f, dB = 0.f, nB = 0.f;
#pragma unroll 4
    for (int i = 0; i < 32; ++i) {
      const int p = ((lane + i) & 31) * 2;
      float4 kk = *(const float4*)&kv[ah][kb + p];   // k0 v0 k1 v1
      float pA0 = __expf(fmaf(q0, kk.x, -m0));
      float pA1 = __expf(fmaf(q0, kk.z, -m0));
      float pB0 = __expf(fmaf(q1, kk.x, -m1));
      float pB1 = __expf(fmaf(q1, kk.z, -m1));
      dA += pA0 + pA1; nA = fmaf(pA1, kk.w, fmaf(pA0, kk.y, nA));
      dB += pB0 + pB1; nB = fmaf(pB1, kk.w, fmaf(pB0, kk.y, nB));
    }
    part[ah][2 * lane][kq]     = make_float2(dA, nA);
    part[ah][2 * lane + 1][kq] = make_float2(dB, nB);
  }
  __syncthreads();

  // ---- combine quarters (threads 0..511): h = t>>7, qr = t&127
  if (t < 512) {
    const int h = t >> 7, qr = t & 127;
    float2 a = part[h][qr][0], b = part[h][qr][1];
    float2 c = part[h][qr][2], d = part[h][qr][3];
    osm[h][qr] = (a.y + b.y + c.y + d.y) / (a.x + b.x + c.x + d.x);
  }
  __syncthreads();

  // ---- Wout proj + residual + LN1 : threads 0..511 -> (r = t>>2, d = t&3)
  if (t < 512) {
    const int r = t >> 2, d = t & 3;
    const float o0 = osm[0][r], o1 = osm[1][r], o2 = osm[2][r], o3 = osm[3][r];
    float rr = XTin[(n * BATCH + base_s + r) * 4 + d] + bo[d]
             + o0*Wo[d*4+0] + o1*Wo[d*4+1] + o2*Wo[d*4+2] + o3*Wo[d*4+3];
    float sum = rr + __shfl_xor(rr, 1, 64); sum += __shfl_xor(sum, 2, 64);
    const float mean = 0.25f * sum;
    const float dv = rr - mean;
    float qq = dv * dv;
    float qs = qq + __shfl_xor(qq, 1, 64); qs += __shfl_xor(qs, 2, 64);
    const float rstd = rsqrtf(0.25f * qs + 1e-5f);
    x1s[r][d] = fmaf(dv * rstd, g1l[d], e1l[d]);
  }
  __syncthreads();

  // ---- FFN: wave wv streams f in [wv*128, wv*128+128) via SCALAR loads;
  //      lane owns rows {lane, 64+lane}. 32 groups of 4 f, unroll 2.
  {
    const int fb = __builtin_amdgcn_readfirstlane(wv) * 128;
    const float* __restrict__ w1p = W1l  + fb * 4;   // wave-uniform base
    const float* __restrict__ w2p = W2Tl + fb * 4;
    const float* __restrict__ b1p = b1l  + fb;
    const float xA0 = x1s[lane][0],    xA1 = x1s[lane][1];
    const float xA2 = x1s[lane][2],    xA3 = x1s[lane][3];
    const float xB0 = x1s[64+lane][0], xB1 = x1s[64+lane][1];
    const float xB2 = x1s[64+lane][2], xB3 = x1s[64+lane][3];
    float aA0=0.f,aA1=0.f,aA2=0.f,aA3=0.f;
    float aB0=0.f,aB1=0.f,aB2=0.f,aB3=0.f;
#pragma unroll 2
    for (int g = 0; g < 32; ++g) {
      float w1v[16], w2v[16], bv[4];
#pragma unroll
      for (int i = 0; i < 16; ++i) w1v[i] = w1p[g * 16 + i];
#pragma unroll
      for (int i = 0; i < 16; ++i) w2v[i] = w2p[g * 16 + i];
#pragma unroll
      for (int i = 0; i < 4; ++i)  bv[i]  = b1p[g * 4 + i];
#pragma unroll
      for (int f = 0; f < 4; ++f) {
        const float w10 = w1v[f*4+0], w11 = w1v[f*4+1];
        const float w12 = w1v[f*4+2], w13 = w1v[f*4+3];
        const float w20 = w2v[f*4+0], w21 = w2v[f*4+1];
        const float w22 = w2v[f*4+2], w23 = w2v[f*4+3];
        float hA = fmaf(xA3, w13, fmaf(xA2, w12, fmaf(xA1, w11, fmaf(xA0, w10, bv[f]))));
        hA = fmaxf(hA, 0.f);
        aA0 = fmaf(hA, w20, aA0); aA1 = fmaf(hA, w21, aA1);
        aA2 = fmaf(hA, w22, aA2); aA3 = fmaf(hA, w23, aA3);
        float hB = fmaf(xB3, w13, fmaf(xB2, w12, fmaf(xB1, w11, fmaf(xB0, w10, bv[f]))));
        hB = fmaxf(hB, 0.f);
        aB0 = fmaf(hB, w20, aB0); aB1 = fmaf(hB, w21, aB1);
        aB2 = fmaf(hB, w22, aB2); aB3 = fmaf(hB, w23, aB3);
      }
    }
    *(float4*)&pacc[wv][lane][0]      = make_float4(aA0, aA1, aA2, aA3);
    *(float4*)&pacc[wv][64 + lane][0] = make_float4(aB0, aB1, aB2, aB3);
  }
  __syncthreads();

  // ---- reduce + residual + LN2 : threads 0..511 -> (r, d)
  if (t < 512) {
    const int r = t >> 2, d = t & 3;
    float s16 = b2l[d];
#pragma unroll
    for (int w = 0; w < 16; ++w) s16 += pacc[w][r][d];
    float val = x1s[r][d] + s16;
    float sum = val + __shfl_xor(val, 1, 64); sum += __shfl_xor(sum, 2, 64);
    const float mean = 0.25f * sum;
    const float dv = val - mean;
    float qq = dv * dv;
    float qs = qq + __shfl_xor(qq, 1, 64); qs += __shfl_xor(qs, 2, 64);
    const float rstd = rsqrtf(0.25f * qs + 1e-5f);
    const float res = fmaf(dv * rstd, g2l[d], e2l[d]);
    if (!last) XTout[(n * BATCH + base_s + r) * 4 + d] = res;
    else       x1s[r][d] = res;   // own element: no race
  }

  // ---- layer 3 only: final linear + softmax over d
  if (last) {
    __syncthreads();
    if (t < 512) {
      const int r = t >> 2, j = t & 3;
      const float y = fmaf(x1s[r][3], Wl[j*4+3], fmaf(x1s[r][2], Wl[j*4+2],
                      fmaf(x1s[r][1], Wl[j*4+1], fmaf(x1s[r][0], Wl[j*4+0], bl[j]))));
      float mx = fmaxf(y, __shfl_xor(y, 1, 64)); mx = fmaxf(mx, __shfl_xor(mx, 2, 64));
      const float e = __expf(y - mx);
      float se = e + __shfl_xor(e, 1, 64); se += __shfl_xor(se, 2, 64);
      out[((base_s + r) * SEQ + n) * 4 + j] = e / se;
    }
  }
}

// ---------------------------------------------------------------- launch
extern "C" void kernel_launch(void* const* d_in, const int* in_sizes, int n_in,
                              void* d_out, int out_size, void* d_ws, size_t ws_size,
                              hipStream_t stream)
{
  const float* x     = (const float*)d_in[0];
  const float* convw = (const float*)d_in[1];
  const float* convb = (const float*)d_in[2];
  const float* Wl    = (const float*)d_in[3];
  const float* bl    = (const float*)d_in[4];
  const float* lng   = (const float*)d_in[5];
  const float* lnb   = (const float*)d_in[6];
  const float* Win   = (const float*)d_in[7];
  const float* bi    = (const float*)d_in[8];
  const float* Wout  = (const float*)d_in[9];
  const float* bout  = (const float*)d_in[10];
  const float* W1    = (const float*)d_in[11];
  const float* b1    = (const float*)d_in[12];
  const float* W2    = (const float*)d_in[13];
  const float* b2    = (const float*)d_in[14];
  const float* g1    = (const float*)d_in[15];
  const float* be1   = (const float*)d_in[16];
  const float* g2    = (const float*)d_in[17];
  const float* be2   = (const float*)d_in[18];

  float* XT0 = (float*)d_ws;                 // [100][256][4]
  float* XT1 = XT0 + SEQ * BATCH * 4;
  float* W2T = XT1 + SEQ * BATCH * 4;        // [4][2048][4]

  k_prep<<<32, 256, 0, stream>>>(W2, W2T);
  k_stageA<<<BATCH, 64, 0, stream>>>(x, convw, convb, Wl, bl, lng, lnb, XT0);
  for (int l = 0; l < 4; ++l) {
    const float* in  = (l & 1) ? XT1 : XT0;
    float*       outb= (l & 1) ? XT0 : XT1;
    k_layer<<<dim3(SEQ, 2), 1024, 0, stream>>>(
        in, outb,
        Win + l * 48, bi + l * 12, Wout + l * 16, bout + l * 4,
        W1 + l * FFD * 4, b1 + l * FFD, W2T + l * FFD * 4, b2 + l * 4,
        g1 + l * 4, be1 + l * 4, g2 + l * 4, be2 + l * 4,
        Wl, bl, (float*)d_out, (l == 3) ? 1 : 0);
  }
}